// Round 5
// baseline (677.596 us; speedup 1.0000x reference)
//
#include <hip/hip_runtime.h>
#include <hip/hip_bf16.h>
#include <math.h>

#define N_USERS   100000
#define N_RECIPES 50000
#define NE        600000
#define NL        200000
#define DU        128
#define DR        256
#define H         128
#define OUT_D     64

// binned CSR constants: 256 WGs, 16 coarse buckets = 16 WG-ranges each
#define NR_R 196    // nodes per WG (recipes): ceil(50000/256)
#define NB_R 3136   // nodes per coarse bucket = 16*NR_R
#define NR_U 391    // ceil(100000/256)
#define NB_U 6256   // 16*NR_U

using half2v = __attribute__((ext_vector_type(2))) _Float16;
using half4v = __attribute__((ext_vector_type(4))) _Float16;
using half8v = __attribute__((ext_vector_type(8))) _Float16;
using f32x4  = __attribute__((ext_vector_type(4))) float;

// ---------------- utility fills ----------------
__global__ void fill_zero_i32(int* __restrict__ p, int n) {
  int i = blockIdx.x * 256 + threadIdx.x;
  if (i < n) p[i] = 0;
}

// ---------------- batched f32 -> fp16 weight conversion ----------------
struct WPack {
  const float* src[10];
  _Float16* dst[10];
  int sz4[10];
};
__global__ void convert_weights(WPack p) {
  const int m = blockIdx.y;
  const int i = blockIdx.x * 256 + threadIdx.x;
  if (i < p.sz4[m]) {
    float4 v = ((const float4*)p.src[m])[i];
    half4v h;
    h[0] = (_Float16)v.x; h[1] = (_Float16)v.y;
    h[2] = (_Float16)v.z; h[3] = (_Float16)v.w;
    ((half4v*)p.dst[m])[i] = h;
  }
}

// ---------------- degree histogram ----------------
__global__ void hist_kernel(const int* __restrict__ esrc, const int* __restrict__ edst,
                            int* __restrict__ cnt_u, int* __restrict__ cnt_r) {
  int i = blockIdx.x * 256 + threadIdx.x;
  if (i < NE) {
    atomicAdd(&cnt_r[edst[i]], 1);
    atomicAdd(&cnt_u[esrc[i]], 1);
  }
}

// ---------------- fused 3-phase exclusive scan (r and u in one launch) ----------------
__global__ void scan_phaseA_both(const int* __restrict__ cnt_r, int* __restrict__ off_r,
                                 int* __restrict__ bsum_r, int nbR,
                                 const int* __restrict__ cnt_u, int* __restrict__ off_u,
                                 int* __restrict__ bsum_u) {
  const bool isR = (int)blockIdx.x < nbR;
  const int blk = isR ? blockIdx.x : blockIdx.x - nbR;
  const int* cnt = isR ? cnt_r : cnt_u;
  int* outx = isR ? off_r : off_u;
  int* bsum = isR ? bsum_r : bsum_u;
  const int n = isR ? N_RECIPES : N_USERS;
  __shared__ int wsum[4];
  int tid = threadIdx.x;
  int lane = tid & 63, wid = tid >> 6;
  int idx = blk * 4096 + tid * 16;
  int v[16];
  int s = 0;
#pragma unroll
  for (int i = 0; i < 16; ++i) {
    int x = (idx + i < n) ? cnt[idx + i] : 0;
    v[i] = s;
    s += x;
  }
  int inc = s;
#pragma unroll
  for (int o = 1; o < 64; o <<= 1) {
    int t = __shfl_up(inc, o, 64);
    if (lane >= o) inc += t;
  }
  if (lane == 63) wsum[wid] = inc;
  __syncthreads();
  int woff = 0;
#pragma unroll
  for (int w = 0; w < 4; ++w)
    if (w < wid) woff += wsum[w];
  int excl = woff + inc - s;
#pragma unroll
  for (int i = 0; i < 16; ++i)
    if (idx + i < n) outx[idx + i] = excl + v[i];
  if (tid == 255) bsum[blk] = woff + inc;
}

__global__ void scan_phaseB_both(int* __restrict__ bsum_r, int nbR, int* __restrict__ off_r,
                                 int* __restrict__ bsum_u, int nbU, int* __restrict__ off_u) {
  const bool isR = threadIdx.x < 64;
  int* bsum = isR ? bsum_r : bsum_u;
  int* offa = isR ? off_r : off_u;
  const int nb = isR ? nbR : nbU;
  const int n = isR ? N_RECIPES : N_USERS;
  int lane = threadIdx.x & 63;
  int v = (lane < nb) ? bsum[lane] : 0;
  int inc = v;
#pragma unroll
  for (int o = 1; o < 64; o <<= 1) {
    int t = __shfl_up(inc, o, 64);
    if (lane >= o) inc += t;
  }
  if (lane < nb) bsum[lane] = inc - v;
  if (lane == 63) offa[n] = inc;
}

__global__ void scan_phaseC_both(int* __restrict__ off_r, const int* __restrict__ bsum_r,
                                 int* __restrict__ off_u, const int* __restrict__ bsum_u) {
  int i = blockIdx.x * 256 + threadIdx.x;
  if (i < N_RECIPES) {
    off_r[i] += bsum_r[i >> 12];
  } else if (i < N_RECIPES + N_USERS) {
    int j = i - N_RECIPES;
    off_u[j] += bsum_u[j >> 12];
  }
}

// ---------------- bin prep: bucket edge-offsets + cursors ----------------
__global__ void prep_bins(const int* __restrict__ off_r, const int* __restrict__ off_u,
                          int* __restrict__ boff_r, int* __restrict__ boff_u,
                          int* __restrict__ bcur_r, int* __restrict__ bcur_u) {
  int t = threadIdx.x;
  if (t < 17) {
    int nr = t * NB_R; if (nr > N_RECIPES) nr = N_RECIPES;
    boff_r[t] = off_r[nr];
    int nu = t * NB_U; if (nu > N_USERS) nu = N_USERS;
    boff_u[t] = off_u[nu];
  }
  if (t < 16) {
    bcur_r[t] = off_r[t * NB_R];
    bcur_u[t] = off_u[t * NB_U];
  }
}

// ---------------- phase 1: bin (payload,key) pairs into 16 coarse buckets ----------------
template <int NBv>
__global__ __launch_bounds__(256) void bin_phase1(
    const int* __restrict__ keys, const int* __restrict__ pays,
    int* __restrict__ bcur, int2* __restrict__ stage) {
  __shared__ int cnt[16];
  __shared__ int gbase[16];
  constexpr int EPT = 8;
  const int BATCH = 256 * EPT;  // 2048
  for (int base = blockIdx.x * BATCH; base < NE; base += gridDim.x * BATCH) {
    if (threadIdx.x < 16) cnt[threadIdx.x] = 0;
    __syncthreads();
    int b_[EPT], r_[EPT], k_[EPT], p_[EPT];
#pragma unroll
    for (int e = 0; e < EPT; ++e) {
      int i = base + threadIdx.x + e * 256;
      if (i < NE) {
        int k = keys[i];
        k_[e] = k;
        p_[e] = pays[i];
        int b = k / NBv;
        b_[e] = b;
        r_[e] = atomicAdd(&cnt[b], 1);
      } else {
        b_[e] = -1;
      }
    }
    __syncthreads();
    if (threadIdx.x < 16 && cnt[threadIdx.x] > 0)
      gbase[threadIdx.x] = atomicAdd(&bcur[threadIdx.x], cnt[threadIdx.x]);
    __syncthreads();
#pragma unroll
    for (int e = 0; e < EPT; ++e) {
      if (b_[e] >= 0)
        stage[gbase[b_[e]] + r_[e]] = make_int2(p_[e], k_[e]);
    }
  }
}

// ---------------- phase 2: WG per node-subrange, scatter within bucket ----------------
template <int Nv, int NRv>
__global__ __launch_bounds__(256) void bin_phase2(
    const int2* __restrict__ stage, const int* __restrict__ boff,
    const int* __restrict__ offx, int* __restrict__ eidx) {
  __shared__ int cur[NRv];
  const int w = blockIdx.x;
  const int n0 = w * NRv;
  const int n1 = min(n0 + NRv, Nv);
  for (int i = threadIdx.x; i < NRv; i += 256) cur[i] = 0;
  __syncthreads();
  const int B = w >> 4;
  const int s = boff[B], e2 = boff[B + 1];
  for (int i = s + threadIdx.x; i < e2; i += 256) {
    int2 pr = stage[i];
    int n = pr.y;
    if (n >= n0 && n < n1) {
      int pos = offx[n] + atomicAdd(&cur[n - n0], 1);
      eidx[pos] = pr.x;
    }
  }
}

// ---------------- segment mean: L=ROWH/8 lanes per node, half8v loads ----------------
template <int ROWH, bool ADD, bool DORELU>
__global__ __launch_bounds__(256) void agg_mean2(
    const _Float16* __restrict__ feat, const int* __restrict__ offx,
    const int* __restrict__ eidx, _Float16* __restrict__ outm, int n_dst) {
  constexpr int L = ROWH / 8;  // 16 (H=128) or 8 (OUT=64)
  const int nid = (int)((blockIdx.x * 256 + threadIdx.x) / L);
  const int ln = threadIdx.x & (L - 1);
  if (nid >= n_dst) return;
  const int s = offx[nid], e = offx[nid + 1];
  float a0[8] = {0}, a1[8] = {0}, a2[8] = {0}, a3[8] = {0};
  int i = s;
  for (; i + 3 < e; i += 4) {
    const int r0 = eidx[i], r1 = eidx[i + 1], r2 = eidx[i + 2], r3 = eidx[i + 3];
    half8v v0 = ((const half8v*)(feat + (size_t)r0 * ROWH))[ln];
    half8v v1 = ((const half8v*)(feat + (size_t)r1 * ROWH))[ln];
    half8v v2 = ((const half8v*)(feat + (size_t)r2 * ROWH))[ln];
    half8v v3 = ((const half8v*)(feat + (size_t)r3 * ROWH))[ln];
#pragma unroll
    for (int t = 0; t < 8; ++t) {
      a0[t] += (float)v0[t];
      a1[t] += (float)v1[t];
      a2[t] += (float)v2[t];
      a3[t] += (float)v3[t];
    }
  }
  for (; i < e; ++i) {
    const int r0 = eidx[i];
    half8v v0 = ((const half8v*)(feat + (size_t)r0 * ROWH))[ln];
#pragma unroll
    for (int t = 0; t < 8; ++t) a0[t] += (float)v0[t];
  }
  const float invc = (e > s) ? 1.f / (float)(e - s) : 0.f;
  half8v o;
  half8v old;
  if (ADD) old = ((const half8v*)(outm + (size_t)nid * ROWH))[ln];
#pragma unroll
  for (int t = 0; t < 8; ++t) {
    float m = (a0[t] + a1[t] + a2[t] + a3[t]) * invc;
    if (ADD) m += (float)old[t];
    if (DORELU) m = fmaxf(m, 0.f);
    o[t] = (_Float16)m;
  }
  ((half8v*)(outm + (size_t)nid * ROWH))[ln] = o;
}

// ---------------- direct-global fp16 MFMA GEMM (no LDS, no barriers) ----------------
// out[M,BN] = act(A1*W1^T (+ A2*W2^T) (+ bias)). W fp16 [BN,K] row-major.
template <int BN, int K, bool DUAL, bool BIAS, bool RELU, bool A_F32>
__global__ __launch_bounds__(256) void gemm_direct(
    const void* __restrict__ A1v, const _Float16* __restrict__ W1,
    const void* __restrict__ A2v, const _Float16* __restrict__ W2,
    const float* __restrict__ bias, _Float16* __restrict__ outp, int M) {
  constexpr int WN = BN / 64;
  constexpr int BM = (4 / WN) * 64;
  const int lane = threadIdx.x & 63;
  const int wid = threadIdx.x >> 6;
  const int wm = wid / WN;
  const int wn = wid % WN;
  const int m0 = blockIdx.x * BM;
  const int lm = lane & 15;
  const int lkb = (lane >> 4) * 8;

  f32x4 acc[4][4];
  const f32x4 zero4 = {0.f, 0.f, 0.f, 0.f};
#pragma unroll
  for (int i = 0; i < 4; ++i)
#pragma unroll
    for (int j = 0; j < 4; ++j) acc[i][j] = zero4;

  int arow[4];
#pragma unroll
  for (int i = 0; i < 4; ++i) {
    int r = m0 + wm * 64 + i * 16 + lm;
    arow[i] = (r < M) ? r : (M - 1);
  }

#pragma unroll
  for (int pass = 0; pass < (DUAL ? 2 : 1); ++pass) {
    const void* Av = pass ? A2v : A1v;
    const _Float16* __restrict__ W = pass ? W2 : W1;
#pragma unroll
    for (int k0 = 0; k0 < K; k0 += 32) {
      half8v af[4], bf[4];
      if constexpr (A_F32) {
        const float* __restrict__ A = (const float*)Av;
#pragma unroll
        for (int i = 0; i < 4; ++i) {
          const float* p = A + (size_t)arow[i] * K + k0 + lkb;
          float4 u = *(const float4*)p;
          float4 v = *(const float4*)(p + 4);
          af[i][0] = (_Float16)u.x; af[i][1] = (_Float16)u.y;
          af[i][2] = (_Float16)u.z; af[i][3] = (_Float16)u.w;
          af[i][4] = (_Float16)v.x; af[i][5] = (_Float16)v.y;
          af[i][6] = (_Float16)v.z; af[i][7] = (_Float16)v.w;
        }
      } else {
        const _Float16* __restrict__ A = (const _Float16*)Av;
#pragma unroll
        for (int i = 0; i < 4; ++i)
          af[i] = *(const half8v*)(A + (size_t)arow[i] * K + k0 + lkb);
      }
#pragma unroll
      for (int j = 0; j < 4; ++j)
        bf[j] = *(const half8v*)(W + (size_t)(wn * 64 + j * 16 + lm) * K + k0 + lkb);
#pragma unroll
      for (int i = 0; i < 4; ++i)
#pragma unroll
        for (int j = 0; j < 4; ++j)
          acc[i][j] = __builtin_amdgcn_mfma_f32_16x16x32_f16(af[i], bf[j], acc[i][j], 0, 0, 0);
    }
  }
  const int rb = (lane >> 4) * 4;
#pragma unroll
  for (int j = 0; j < 4; ++j) {
    const int col = wn * 64 + j * 16 + lm;
    float bj = 0.f;
    if constexpr (BIAS) bj = bias[col];
#pragma unroll
    for (int i = 0; i < 4; ++i) {
#pragma unroll
      for (int r = 0; r < 4; ++r) {
        const int grow = m0 + wm * 64 + i * 16 + rb + r;
        if (grow < M) {
          float v = acc[i][j][r] + bj;
          if (RELU) v = fmaxf(v, 0.f);
          outp[(size_t)grow * BN + col] = (_Float16)v;
        }
      }
    }
  }
}

// ---------------- decoder: one wave per label pair ----------------
__global__ __launch_bounds__(256) void decoder_f16(
    const _Float16* __restrict__ zu, const _Float16* __restrict__ zr,
    const int* __restrict__ ls, const int* __restrict__ ld,
    float* __restrict__ outp) {
  const int w = (blockIdx.x * 256 + threadIdx.x) >> 6;
  if (w >= NL) return;
  const int lane = threadIdx.x & 63;
  const int hl = lane & 31;
  const _Float16* src = (lane >= 32) ? (zr + (size_t)ld[w] * OUT_D)
                                     : (zu + (size_t)ls[w] * OUT_D);
  half2v v = ((const half2v*)src)[hl];
  float x0 = (float)v[0], x1 = (float)v[1];
  float y0 = __shfl_xor(x0, 32, 64);
  float y1 = __shfl_xor(x1, 32, 64);
  float nx = x0 * x0 + x1 * x1;
  float ny = y0 * y0 + y1 * y1;
  float ab = x0 * y0 + x1 * y1;
#pragma unroll
  for (int o = 16; o > 0; o >>= 1) {
    nx += __shfl_xor(nx, o, 64);
    ny += __shfl_xor(ny, o, 64);
    ab += __shfl_xor(ab, o, 64);
  }
  if (lane == 0) {
    float denom = fmaxf(sqrtf(nx), 1e-12f) * fmaxf(sqrtf(ny), 1e-12f);
    outp[w] = ab / denom;
  }
}

extern "C" void kernel_launch(void* const* d_in, const int* in_sizes, int n_in,
                              void* d_out, int out_size, void* d_ws, size_t ws_size,
                              hipStream_t stream) {
  (void)in_sizes; (void)n_in; (void)out_size; (void)ws_size;
  const float* x_user   = (const float*)d_in[0];
  const float* x_recipe = (const float*)d_in[1];
  const int* edge_src   = (const int*)d_in[2];
  const int* edge_dst   = (const int*)d_in[3];
  const int* lbl_src    = (const int*)d_in[4];
  const int* lbl_dst    = (const int*)d_in[5];
  const float* Wu       = (const float*)d_in[6];
  const float* bu       = (const float*)d_in[7];
  const float* Wrec     = (const float*)d_in[8];
  const float* brec     = (const float*)d_in[9];
  const float* c1_ur_Wl = (const float*)d_in[10];
  const float* c1_ur_bl = (const float*)d_in[11];
  const float* c1_ur_Wr = (const float*)d_in[12];
  const float* c1_ru_Wl = (const float*)d_in[13];
  const float* c1_ru_bl = (const float*)d_in[14];
  const float* c1_ru_Wr = (const float*)d_in[15];
  const float* c2_ur_Wl = (const float*)d_in[16];
  const float* c2_ur_bl = (const float*)d_in[17];
  const float* c2_ur_Wr = (const float*)d_in[18];
  const float* c2_ru_Wl = (const float*)d_in[19];
  const float* c2_ru_bl = (const float*)d_in[20];
  const float* c2_ru_Wr = (const float*)d_in[21];
  float* out = (float*)d_out;

  char* ws = (char*)d_ws;
  size_t off = 0;
  auto take = [&](size_t bytes) -> void* {
    void* p = ws + off;
    off = (off + bytes + 255) & ~(size_t)255;
    return p;
  };
  _Float16* hu     = (_Float16*)take((size_t)N_USERS * H * 2);    // 25.6 MB
  _Float16* hr     = (_Float16*)take((size_t)N_RECIPES * H * 2);  // 12.8 MB
  _Float16* meanr  = (_Float16*)take((size_t)N_RECIPES * H * 2);  // 12.8 MB (also t_r1, t_r2)
  _Float16* r1     = (_Float16*)take((size_t)N_RECIPES * H * 2);  // 12.8 MB
  _Float16* u1     = (_Float16*)take((size_t)N_USERS * H * 2);    // 25.6 MB
  int* cnt_all = (int*)take((size_t)(N_RECIPES + N_USERS) * 4);
  int* cnt_r = cnt_all;
  int* cnt_u = cnt_all + N_RECIPES;
  int* off_r  = (int*)take((size_t)(N_RECIPES + 1) * 4);
  int* off_u  = (int*)take((size_t)(N_USERS + 1) * 4);
  int* eidx_r = (int*)take((size_t)NE * 4);
  int* eidx_u = (int*)take((size_t)NE * 4);
  int2* stage_r = (int2*)take((size_t)NE * 8);
  int2* stage_u = (int2*)take((size_t)NE * 8);
  int* bsum_r = (int*)take(64 * 4);
  int* bsum_u = (int*)take(64 * 4);
  int* boff_r = (int*)take(32 * 4);
  int* boff_u = (int*)take(32 * 4);
  int* bcur_r = (int*)take(16 * 4);
  int* bcur_u = (int*)take(16 * 4);
  _Float16* Wu_h     = (_Float16*)take(H * DU * 2);
  _Float16* Wrec_h   = (_Float16*)take(H * DR * 2);
  _Float16* c1urWl_h = (_Float16*)take(H * H * 2);
  _Float16* c1urWr_h = (_Float16*)take(H * H * 2);
  _Float16* c1ruWl_h = (_Float16*)take(H * H * 2);
  _Float16* c1ruWr_h = (_Float16*)take(H * H * 2);
  _Float16* c2urWl_h = (_Float16*)take(OUT_D * H * 2);
  _Float16* c2urWr_h = (_Float16*)take(OUT_D * H * 2);
  _Float16* c2ruWl_h = (_Float16*)take(OUT_D * H * 2);
  _Float16* c2ruWr_h = (_Float16*)take(OUT_D * H * 2);
  // aliases (dead-buffer reuse; see schedule comments below)
  _Float16* t_r1 = meanr;              // 50k x 128, written after conv1-r GEMM
  _Float16* t_u2 = hr;                 // 100k x 64 = 12.8 MB, after hr dead
  _Float16* t_r2 = meanr;              // 50k x 64, after t_r1 dead
  _Float16* zr   = hu;                 // 50k x 64 = 6.4 MB, after hu dead
  _Float16* zu   = hu + (size_t)N_RECIPES * OUT_D;  // 100k x 64 = 12.8 MB

  // ---- weight conversion (single batched launch)
  WPack wp;
  wp.src[0] = Wu;       wp.dst[0] = Wu_h;      wp.sz4[0] = H * DU / 4;
  wp.src[1] = Wrec;     wp.dst[1] = Wrec_h;    wp.sz4[1] = H * DR / 4;
  wp.src[2] = c1_ur_Wl; wp.dst[2] = c1urWl_h;  wp.sz4[2] = H * H / 4;
  wp.src[3] = c1_ur_Wr; wp.dst[3] = c1urWr_h;  wp.sz4[3] = H * H / 4;
  wp.src[4] = c1_ru_Wl; wp.dst[4] = c1ruWl_h;  wp.sz4[4] = H * H / 4;
  wp.src[5] = c1_ru_Wr; wp.dst[5] = c1ruWr_h;  wp.sz4[5] = H * H / 4;
  wp.src[6] = c2_ur_Wl; wp.dst[6] = c2urWl_h;  wp.sz4[6] = OUT_D * H / 4;
  wp.src[7] = c2_ur_Wr; wp.dst[7] = c2urWr_h;  wp.sz4[7] = OUT_D * H / 4;
  wp.src[8] = c2_ru_Wl; wp.dst[8] = c2ruWl_h;  wp.sz4[8] = OUT_D * H / 4;
  wp.src[9] = c2_ru_Wr; wp.dst[9] = c2ruWr_h;  wp.sz4[9] = OUT_D * H / 4;
  convert_weights<<<dim3(32, 10), 256, 0, stream>>>(wp);

  // ---- CSR build: hist -> scan -> binned two-phase scatter
  const int nbR = (N_RECIPES + 4095) / 4096;  // 13
  const int nbU = (N_USERS + 4095) / 4096;    // 25
  fill_zero_i32<<<(N_RECIPES + N_USERS + 255) / 256, 256, 0, stream>>>(
      cnt_all, N_RECIPES + N_USERS);
  hist_kernel<<<(NE + 255) / 256, 256, 0, stream>>>(edge_src, edge_dst, cnt_u, cnt_r);
  scan_phaseA_both<<<nbR + nbU, 256, 0, stream>>>(cnt_r, off_r, bsum_r, nbR,
                                                  cnt_u, off_u, bsum_u);
  scan_phaseB_both<<<1, 128, 0, stream>>>(bsum_r, nbR, off_r, bsum_u, nbU, off_u);
  scan_phaseC_both<<<(N_RECIPES + N_USERS + 255) / 256, 256, 0, stream>>>(
      off_r, bsum_r, off_u, bsum_u);
  prep_bins<<<1, 64, 0, stream>>>(off_r, off_u, boff_r, boff_u, bcur_r, bcur_u);
  bin_phase1<NB_R><<<(NE + 2047) / 2048, 256, 0, stream>>>(edge_dst, edge_src, bcur_r, stage_r);
  bin_phase1<NB_U><<<(NE + 2047) / 2048, 256, 0, stream>>>(edge_src, edge_dst, bcur_u, stage_u);
  bin_phase2<N_RECIPES, NR_R><<<256, 256, 0, stream>>>(stage_r, boff_r, off_r, eidx_r);
  bin_phase2<N_USERS, NR_U><<<256, 256, 0, stream>>>(stage_u, boff_u, off_u, eidx_u);

  // ---- input projections
  gemm_direct<128, DU, false, true, false, true><<<(N_USERS + 127) / 128, 256, 0, stream>>>(
      x_user, Wu_h, nullptr, nullptr, bu, hu, N_USERS);
  gemm_direct<128, DR, false, true, false, true><<<(N_RECIPES + 127) / 128, 256, 0, stream>>>(
      x_recipe, Wrec_h, nullptr, nullptr, brec, hr, N_RECIPES);

  // ---- conv1, recipe side (dst=50k < src=100k: mean-first)
  agg_mean2<H, false, false><<<(N_RECIPES * 16 + 255) / 256, 256, 0, stream>>>(
      hu, off_r, eidx_r, meanr, N_RECIPES);
  gemm_direct<128, H, true, true, true, false><<<(N_RECIPES + 127) / 128, 256, 0, stream>>>(
      meanr, c1urWl_h, hr, c1urWr_h, c1_ur_bl, r1, N_RECIPES);
  // ---- conv1, user side (src=50k < dst=100k: transform-first)
  gemm_direct<128, H, false, false, false, false><<<(N_RECIPES + 127) / 128, 256, 0, stream>>>(
      hr, c1ruWl_h, nullptr, nullptr, nullptr, t_r1, N_RECIPES);       // t_r1 = hr @ Wl^T
  gemm_direct<128, H, false, true, false, false><<<(N_USERS + 127) / 128, 256, 0, stream>>>(
      hu, c1ruWr_h, nullptr, nullptr, c1_ru_bl, u1, N_USERS);          // u1 = hu @ Wr^T + b
  agg_mean2<H, true, true><<<(N_USERS * 16 + 255) / 256, 256, 0, stream>>>(
      t_r1, off_u, eidx_u, u1, N_USERS);                               // u1 = relu(u1 + mean)

  // ---- conv2, recipe side (transform-first: agg rows shrink to 64)
  gemm_direct<64, H, false, false, false, false><<<(N_USERS + 255) / 256, 256, 0, stream>>>(
      u1, c2urWl_h, nullptr, nullptr, nullptr, t_u2, N_USERS);         // t_u2 = u1 @ Wl^T
  gemm_direct<64, H, false, true, false, false><<<(N_RECIPES + 255) / 256, 256, 0, stream>>>(
      r1, c2urWr_h, nullptr, nullptr, c2_ur_bl, zr, N_RECIPES);        // zr = r1 @ Wr^T + b
  agg_mean2<OUT_D, true, false><<<(N_RECIPES * 8 + 255) / 256, 256, 0, stream>>>(
      t_u2, off_r, eidx_r, zr, N_RECIPES);                             // zr += mean
  // ---- conv2, user side
  gemm_direct<64, H, false, false, false, false><<<(N_RECIPES + 255) / 256, 256, 0, stream>>>(
      r1, c2ruWl_h, nullptr, nullptr, nullptr, t_r2, N_RECIPES);       // t_r2 = r1 @ Wl^T
  gemm_direct<64, H, false, true, false, false><<<(N_USERS + 255) / 256, 256, 0, stream>>>(
      u1, c2ruWr_h, nullptr, nullptr, c2_ru_bl, zu, N_USERS);          // zu = u1 @ Wr^T + b
  agg_mean2<OUT_D, true, false><<<(N_USERS * 8 + 255) / 256, 256, 0, stream>>>(
      t_r2, off_u, eidx_u, zu, N_USERS);                               // zu += mean

  // ---- decoder
  decoder_f16<<<((size_t)NL * 64 + 255) / 256, 256, 0, stream>>>(zu, zr, lbl_src, lbl_dst, out);
}

// Round 6
// 498.927 us; speedup vs baseline: 1.3581x; 1.3581x over previous
//
#include <hip/hip_runtime.h>
#include <hip/hip_bf16.h>
#include <math.h>

#define N_USERS   100000
#define N_RECIPES 50000
#define NE        600000
#define NL        200000
#define DU        128
#define DR        256
#define H         128
#define OUT_D     64

// CSR binning: 256 buckets per direction; bucket == one phase2-WG node range
#define NBKT 256
#define NB_R 196   // ceil(50000/256)
#define NB_U 391   // ceil(100000/256)

using half2v = __attribute__((ext_vector_type(2))) _Float16;
using half4v = __attribute__((ext_vector_type(4))) _Float16;
using half8v = __attribute__((ext_vector_type(8))) _Float16;
using f32x4  = __attribute__((ext_vector_type(4))) float;

__device__ __forceinline__ int wave_incl_scan(int v, int lane) {
#pragma unroll
  for (int o = 1; o < 64; o <<= 1) {
    int t = __shfl_up(v, o, 64);
    if (lane >= o) v += t;
  }
  return v;
}

// ---------------- batched f32 -> fp16 weight conversion (+ btot zero) ----------------
struct WPack {
  const float* src[10];
  _Float16* dst[10];
  int sz4[10];
  int* btot;  // [512] zeroed by block (0,0)
};
__global__ void convert_weights(WPack p) {
  const int m = blockIdx.y;
  const int i = blockIdx.x * 256 + threadIdx.x;
  if (m == 0 && blockIdx.x == 0) {
    p.btot[threadIdx.x] = 0;
    p.btot[threadIdx.x + 256] = 0;
  }
  if (i < p.sz4[m]) {
    float4 v = ((const float4*)p.src[m])[i];
    half4v h;
    h[0] = (_Float16)v.x; h[1] = (_Float16)v.y;
    h[2] = (_Float16)v.z; h[3] = (_Float16)v.w;
    ((half4v*)p.dst[m])[i] = h;
  }
}

// ---------------- CSR phase 0: per-bucket totals (both directions) ----------------
__global__ __launch_bounds__(256) void csr_phase0(const int* __restrict__ esrc,
                                                  const int* __restrict__ edst,
                                                  int* __restrict__ btot) {
  __shared__ int h[512];
  const int tid = threadIdx.x;
  h[tid] = 0; h[tid + 256] = 0;
  __syncthreads();
  for (int i = blockIdx.x * 256 + tid; i < NE; i += gridDim.x * 256) {
    atomicAdd(&h[edst[i] / NB_R], 1);
    atomicAdd(&h[256 + esrc[i] / NB_U], 1);
  }
  __syncthreads();
  if (h[tid]) atomicAdd(&btot[tid], h[tid]);
  if (h[tid + 256]) atomicAdd(&btot[tid + 256], h[tid + 256]);
}

// ---------------- CSR bucket scan: bases + cursors (1 WG) ----------------
__global__ void csr_bscan(const int* __restrict__ btot,
                          int* __restrict__ bbase_r, int* __restrict__ bcur_r,
                          int* __restrict__ off_r,
                          int* __restrict__ bbase_u, int* __restrict__ bcur_u,
                          int* __restrict__ off_u) {
  __shared__ int wsum[4];
  const int tid = threadIdx.x, lane = tid & 63, wid = tid >> 6;
#pragma unroll
  for (int dir = 0; dir < 2; ++dir) {
    int v = btot[dir * 256 + tid];
    int inc = wave_incl_scan(v, lane);
    if (lane == 63) wsum[wid] = inc;
    __syncthreads();
    int woff = 0;
#pragma unroll
    for (int w = 0; w < 4; ++w)
      if (w < wid) woff += wsum[w];
    int excl = woff + inc - v;
    int* bbase = dir ? bbase_u : bbase_r;
    int* bcur = dir ? bcur_u : bcur_r;
    bbase[tid] = excl;
    bcur[tid] = excl;
    if (tid == 255) bbase[256] = excl + v;  // == NE
    __syncthreads();
  }
  if (tid == 0) {
    off_r[N_RECIPES] = NE;
    off_u[N_USERS] = NE;
  }
}

// ---------------- CSR phase 1: bin packed pairs into bucket regions ----------------
// packed = (local_node << 17) | payload   (payload < 2^17, local < 512)
__global__ __launch_bounds__(256) void csr_phase1(
    const int* __restrict__ esrc, const int* __restrict__ edst,
    int* __restrict__ bcur_r, int* __restrict__ bcur_u,
    unsigned* __restrict__ stage_r, unsigned* __restrict__ stage_u) {
  __shared__ int cnt[512];
  __shared__ int gbase[512];
  constexpr int EPT = 8;
  const int BATCH = 256 * EPT;
  const int tid = threadIdx.x;
  for (int base = blockIdx.x * BATCH; base < NE; base += gridDim.x * BATCH) {
    cnt[tid] = 0; cnt[tid + 256] = 0;
    __syncthreads();
    int s_[EPT], d_[EPT], rr_[EPT], ru_[EPT];
#pragma unroll
    for (int e = 0; e < EPT; ++e) {
      const int i = base + e * 256 + tid;
      if (i < NE) {
        const int s = esrc[i], d = edst[i];
        s_[e] = s; d_[e] = d;
        rr_[e] = atomicAdd(&cnt[d / NB_R], 1);
        ru_[e] = atomicAdd(&cnt[256 + s / NB_U], 1);
      } else {
        d_[e] = -1;
      }
    }
    __syncthreads();
    if (cnt[tid]) gbase[tid] = atomicAdd(&bcur_r[tid], cnt[tid]);
    if (cnt[tid + 256]) gbase[tid + 256] = atomicAdd(&bcur_u[tid], cnt[tid + 256]);
    __syncthreads();
#pragma unroll
    for (int e = 0; e < EPT; ++e) {
      if (d_[e] >= 0) {
        const int br = d_[e] / NB_R, lr = d_[e] - br * NB_R;
        stage_r[gbase[br] + rr_[e]] = ((unsigned)lr << 17) | (unsigned)s_[e];
        const int bu = s_[e] / NB_U, lu = s_[e] - bu * NB_U;
        stage_u[gbase[256 + bu] + ru_[e]] = ((unsigned)lu << 17) | (unsigned)d_[e];
      }
    }
    __syncthreads();
  }
}

// ---------------- CSR phase 2: one WG per bucket -> offx + eidx ----------------
template <int Nv, int NBv>
__device__ __forceinline__ void phase2_impl(int* cnt, int* wsum,
                                            const unsigned* __restrict__ stage,
                                            const int* __restrict__ bbase,
                                            int* __restrict__ offx,
                                            int* __restrict__ eidx, int B) {
  const int tid = threadIdx.x, lane = tid & 63, wid = tid >> 6;
  const int n0 = B * NBv;
  const int nloc = min(NBv, Nv - n0);
  cnt[tid] = 0; cnt[tid + 256] = 0;
  __syncthreads();
  const int s = bbase[B], e = bbase[B + 1];
  for (int i = s + tid; i < e; i += 256)
    atomicAdd(&cnt[stage[i] >> 17], 1);
  __syncthreads();
  const int e0 = cnt[2 * tid], e1 = cnt[2 * tid + 1];
  const int ssum = e0 + e1;
  int inc = wave_incl_scan(ssum, lane);
  if (lane == 63) wsum[wid] = inc;
  __syncthreads();
  int woff = 0;
#pragma unroll
  for (int w = 0; w < 4; ++w)
    if (w < wid) woff += wsum[w];
  const int base = s + woff + inc - ssum;  // absolute CSR offset of slot 2*tid
  if (2 * tid < nloc) offx[n0 + 2 * tid] = base;
  if (2 * tid + 1 < nloc) offx[n0 + 2 * tid + 1] = base + e0;
  cnt[2 * tid] = base;
  cnt[2 * tid + 1] = base + e0;
  __syncthreads();
  for (int i = s + tid; i < e; i += 256) {
    const unsigned p = stage[i];
    const int pos = atomicAdd(&cnt[p >> 17], 1);
    eidx[pos] = (int)(p & 0x1FFFFu);
  }
}

__global__ __launch_bounds__(256) void csr_phase2(
    const unsigned* __restrict__ stage_r, const int* __restrict__ bbase_r,
    int* __restrict__ off_r, int* __restrict__ eidx_r,
    const unsigned* __restrict__ stage_u, const int* __restrict__ bbase_u,
    int* __restrict__ off_u, int* __restrict__ eidx_u) {
  __shared__ int cnt[512];
  __shared__ int wsum[4];
  if (blockIdx.x < NBKT)
    phase2_impl<N_RECIPES, NB_R>(cnt, wsum, stage_r, bbase_r, off_r, eidx_r, blockIdx.x);
  else
    phase2_impl<N_USERS, NB_U>(cnt, wsum, stage_u, bbase_u, off_u, eidx_u, blockIdx.x - NBKT);
}

// ---------------- segment mean: L=ROWH/8 lanes per node, half8v loads ----------------
template <int ROWH, bool ADD, bool DORELU>
__global__ __launch_bounds__(256) void agg_mean2(
    const _Float16* __restrict__ feat, const int* __restrict__ offx,
    const int* __restrict__ eidx, _Float16* __restrict__ outm, int n_dst) {
  constexpr int L = ROWH / 8;
  const int nid = (int)((blockIdx.x * 256 + threadIdx.x) / L);
  const int ln = threadIdx.x & (L - 1);
  if (nid >= n_dst) return;
  const int s = offx[nid], e = offx[nid + 1];
  float a0[8] = {0}, a1[8] = {0}, a2[8] = {0}, a3[8] = {0};
  int i = s;
  for (; i + 3 < e; i += 4) {
    const int r0 = eidx[i], r1 = eidx[i + 1], r2 = eidx[i + 2], r3 = eidx[i + 3];
    half8v v0 = ((const half8v*)(feat + (size_t)r0 * ROWH))[ln];
    half8v v1 = ((const half8v*)(feat + (size_t)r1 * ROWH))[ln];
    half8v v2 = ((const half8v*)(feat + (size_t)r2 * ROWH))[ln];
    half8v v3 = ((const half8v*)(feat + (size_t)r3 * ROWH))[ln];
#pragma unroll
    for (int t = 0; t < 8; ++t) {
      a0[t] += (float)v0[t];
      a1[t] += (float)v1[t];
      a2[t] += (float)v2[t];
      a3[t] += (float)v3[t];
    }
  }
  for (; i < e; ++i) {
    const int r0 = eidx[i];
    half8v v0 = ((const half8v*)(feat + (size_t)r0 * ROWH))[ln];
#pragma unroll
    for (int t = 0; t < 8; ++t) a0[t] += (float)v0[t];
  }
  const float invc = (e > s) ? 1.f / (float)(e - s) : 0.f;
  half8v o, old;
  if (ADD) old = ((const half8v*)(outm + (size_t)nid * ROWH))[ln];
#pragma unroll
  for (int t = 0; t < 8; ++t) {
    float m = (a0[t] + a1[t] + a2[t] + a3[t]) * invc;
    if (ADD) m += (float)old[t];
    if (DORELU) m = fmaxf(m, 0.f);
    o[t] = (_Float16)m;
  }
  ((half8v*)(outm + (size_t)nid * ROWH))[ln] = o;
}

// ---------------- dual-table segment mean (conv2: both directions, ROWH=64) ----------------
__global__ __launch_bounds__(256) void agg_mean_dual64(
    const _Float16* __restrict__ fA, const int* __restrict__ offA,
    const int* __restrict__ eA, _Float16* __restrict__ oA,
    const _Float16* __restrict__ fB, const int* __restrict__ offB,
    const int* __restrict__ eB, _Float16* __restrict__ oB) {
  const int gnid = (int)((blockIdx.x * 256 + threadIdx.x) >> 3);
  const int ln = threadIdx.x & 7;
  if (gnid >= N_RECIPES + N_USERS) return;
  const _Float16* feat;
  const int* offx;
  const int* eidx;
  _Float16* outm;
  int nid;
  if (gnid < N_RECIPES) {
    feat = fA; offx = offA; eidx = eA; outm = oA; nid = gnid;
  } else {
    feat = fB; offx = offB; eidx = eB; outm = oB; nid = gnid - N_RECIPES;
  }
  const int s = offx[nid], e = offx[nid + 1];
  float a0[8] = {0}, a1[8] = {0}, a2[8] = {0}, a3[8] = {0};
  int i = s;
  for (; i + 3 < e; i += 4) {
    const int r0 = eidx[i], r1 = eidx[i + 1], r2 = eidx[i + 2], r3 = eidx[i + 3];
    half8v v0 = ((const half8v*)(feat + (size_t)r0 * OUT_D))[ln];
    half8v v1 = ((const half8v*)(feat + (size_t)r1 * OUT_D))[ln];
    half8v v2 = ((const half8v*)(feat + (size_t)r2 * OUT_D))[ln];
    half8v v3 = ((const half8v*)(feat + (size_t)r3 * OUT_D))[ln];
#pragma unroll
    for (int t = 0; t < 8; ++t) {
      a0[t] += (float)v0[t];
      a1[t] += (float)v1[t];
      a2[t] += (float)v2[t];
      a3[t] += (float)v3[t];
    }
  }
  for (; i < e; ++i) {
    const int r0 = eidx[i];
    half8v v0 = ((const half8v*)(feat + (size_t)r0 * OUT_D))[ln];
#pragma unroll
    for (int t = 0; t < 8; ++t) a0[t] += (float)v0[t];
  }
  const float invc = (e > s) ? 1.f / (float)(e - s) : 0.f;
  half8v old = ((const half8v*)(outm + (size_t)nid * OUT_D))[ln];
  half8v o;
#pragma unroll
  for (int t = 0; t < 8; ++t)
    o[t] = (_Float16)((a0[t] + a1[t] + a2[t] + a3[t]) * invc + (float)old[t]);
  ((half8v*)(outm + (size_t)nid * OUT_D))[ln] = o;
}

// ---------------- single dual-input MFMA GEMM (conv1-r: relu(mean@Wl + hr@Wr + b)) ----------------
template <int BN, int K, bool DUAL, bool BIAS, bool RELU, bool A_F32>
__global__ __launch_bounds__(256) void gemm_direct(
    const void* __restrict__ A1v, const _Float16* __restrict__ W1,
    const void* __restrict__ A2v, const _Float16* __restrict__ W2,
    const float* __restrict__ bias, _Float16* __restrict__ outp, int M) {
  constexpr int WN = BN / 64;
  constexpr int BM = (4 / WN) * 64;
  const int lane = threadIdx.x & 63;
  const int wid = threadIdx.x >> 6;
  const int wm = wid / WN;
  const int wn = wid % WN;
  const int m0 = blockIdx.x * BM;
  const int lm = lane & 15;
  const int lkb = (lane >> 4) * 8;

  f32x4 acc[4][4];
  const f32x4 zero4 = {0.f, 0.f, 0.f, 0.f};
#pragma unroll
  for (int i = 0; i < 4; ++i)
#pragma unroll
    for (int j = 0; j < 4; ++j) acc[i][j] = zero4;

  int arow[4];
#pragma unroll
  for (int i = 0; i < 4; ++i) {
    int r = m0 + wm * 64 + i * 16 + lm;
    arow[i] = (r < M) ? r : (M - 1);
  }

#pragma unroll
  for (int pass = 0; pass < (DUAL ? 2 : 1); ++pass) {
    const void* Av = pass ? A2v : A1v;
    const _Float16* __restrict__ W = pass ? W2 : W1;
#pragma unroll
    for (int k0 = 0; k0 < K; k0 += 32) {
      half8v af[4], bf[4];
      if constexpr (A_F32) {
        const float* __restrict__ A = (const float*)Av;
#pragma unroll
        for (int i = 0; i < 4; ++i) {
          const float* p = A + (size_t)arow[i] * K + k0 + lkb;
          float4 u = *(const float4*)p;
          float4 v = *(const float4*)(p + 4);
          af[i][0] = (_Float16)u.x; af[i][1] = (_Float16)u.y;
          af[i][2] = (_Float16)u.z; af[i][3] = (_Float16)u.w;
          af[i][4] = (_Float16)v.x; af[i][5] = (_Float16)v.y;
          af[i][6] = (_Float16)v.z; af[i][7] = (_Float16)v.w;
        }
      } else {
        const _Float16* __restrict__ A = (const _Float16*)Av;
#pragma unroll
        for (int i = 0; i < 4; ++i)
          af[i] = *(const half8v*)(A + (size_t)arow[i] * K + k0 + lkb);
      }
#pragma unroll
      for (int j = 0; j < 4; ++j)
        bf[j] = *(const half8v*)(W + (size_t)(wn * 64 + j * 16 + lm) * K + k0 + lkb);
#pragma unroll
      for (int i = 0; i < 4; ++i)
#pragma unroll
        for (int j = 0; j < 4; ++j)
          acc[i][j] = __builtin_amdgcn_mfma_f32_16x16x32_f16(af[i], bf[j], acc[i][j], 0, 0, 0);
    }
  }
  const int rb = (lane >> 4) * 4;
#pragma unroll
  for (int j = 0; j < 4; ++j) {
    const int col = wn * 64 + j * 16 + lm;
    float bj = 0.f;
    if constexpr (BIAS) bj = bias[col];
#pragma unroll
    for (int i = 0; i < 4; ++i) {
#pragma unroll
      for (int r = 0; r < 4; ++r) {
        const int grow = m0 + wm * 64 + i * 16 + rb + r;
        if (grow < M) {
          float v = acc[i][j][r] + bj;
          if (RELU) v = fmaxf(v, 0.f);
          outp[(size_t)grow * BN + col] = (_Float16)v;
        }
      }
    }
  }
}

// ---------------- multi-part MFMA GEMM (up to 4 independent GEMMs, one dispatch) ----------------
struct GParts {
  const void* A[4];
  const _Float16* W[4];
  const float* bias[4];
  _Float16* out[4];
  int M[4];
  int K[4];
  int blk0[4];  // start block of each part; unused -> INT_MAX
};

template <int BN, bool A_F32>
__global__ __launch_bounds__(256) void gemm_parts(GParts P) {
  constexpr int WN = BN / 64;
  constexpr int BM = (4 / WN) * 64;
  const int bid = blockIdx.x;
  const int p = (bid >= P.blk0[1]) + (bid >= P.blk0[2]) + (bid >= P.blk0[3]);
  const int K = P.K[p];
  const int M = P.M[p];
  const int m0 = (bid - P.blk0[p]) * BM;
  const _Float16* __restrict__ W = P.W[p];
  const float* __restrict__ bias = P.bias[p];
  _Float16* __restrict__ outp = P.out[p];

  const int lane = threadIdx.x & 63;
  const int wid = threadIdx.x >> 6;
  const int wm = wid / WN;
  const int wn = wid % WN;
  const int lm = lane & 15;
  const int lkb = (lane >> 4) * 8;

  f32x4 acc[4][4];
  const f32x4 zero4 = {0.f, 0.f, 0.f, 0.f};
#pragma unroll
  for (int i = 0; i < 4; ++i)
#pragma unroll
    for (int j = 0; j < 4; ++j) acc[i][j] = zero4;

  int arow[4];
#pragma unroll
  for (int i = 0; i < 4; ++i) {
    int r = m0 + wm * 64 + i * 16 + lm;
    arow[i] = (r < M) ? r : (M - 1);
  }

  if constexpr (A_F32) {
    const float* ap[4];
    const _Float16* wp_[4];
#pragma unroll
    for (int i = 0; i < 4; ++i) ap[i] = (const float*)P.A[p] + (size_t)arow[i] * K + lkb;
#pragma unroll
    for (int j = 0; j < 4; ++j) wp_[j] = W + (size_t)(wn * 64 + j * 16 + lm) * K + lkb;
    for (int k0 = 0; k0 < K; k0 += 32) {
      half8v af[4], bf[4];
#pragma unroll
      for (int i = 0; i < 4; ++i) {
        float4 u = *(const float4*)ap[i];
        float4 v = *(const float4*)(ap[i] + 4);
        af[i][0] = (_Float16)u.x; af[i][1] = (_Float16)u.y;
        af[i][2] = (_Float16)u.z; af[i][3] = (_Float16)u.w;
        af[i][4] = (_Float16)v.x; af[i][5] = (_Float16)v.y;
        af[i][6] = (_Float16)v.z; af[i][7] = (_Float16)v.w;
        ap[i] += 32;
      }
#pragma unroll
      for (int j = 0; j < 4; ++j) {
        bf[j] = *(const half8v*)wp_[j];
        wp_[j] += 32;
      }
#pragma unroll
      for (int i = 0; i < 4; ++i)
#pragma unroll
        for (int j = 0; j < 4; ++j)
          acc[i][j] = __builtin_amdgcn_mfma_f32_16x16x32_f16(af[i], bf[j], acc[i][j], 0, 0, 0);
    }
  } else {
    const _Float16* ap[4];
    const _Float16* wp_[4];
#pragma unroll
    for (int i = 0; i < 4; ++i) ap[i] = (const _Float16*)P.A[p] + (size_t)arow[i] * K + lkb;
#pragma unroll
    for (int j = 0; j < 4; ++j) wp_[j] = W + (size_t)(wn * 64 + j * 16 + lm) * K + lkb;
    for (int k0 = 0; k0 < K; k0 += 32) {
      half8v af[4], bf[4];
#pragma unroll
      for (int i = 0; i < 4; ++i) {
        af[i] = *(const half8v*)ap[i];
        ap[i] += 32;
      }
#pragma unroll
      for (int j = 0; j < 4; ++j) {
        bf[j] = *(const half8v*)wp_[j];
        wp_[j] += 32;
      }
#pragma unroll
      for (int i = 0; i < 4; ++i)
#pragma unroll
        for (int j = 0; j < 4; ++j)
          acc[i][j] = __builtin_amdgcn_mfma_f32_16x16x32_f16(af[i], bf[j], acc[i][j], 0, 0, 0);
    }
  }

  const int rb = (lane >> 4) * 4;
#pragma unroll
  for (int j = 0; j < 4; ++j) {
    const int col = wn * 64 + j * 16 + lm;
    const float bj = bias ? bias[col] : 0.f;
#pragma unroll
    for (int i = 0; i < 4; ++i) {
#pragma unroll
      for (int r = 0; r < 4; ++r) {
        const int grow = m0 + wm * 64 + i * 16 + rb + r;
        if (grow < M)
          outp[(size_t)grow * BN + col] = (_Float16)(acc[i][j][r] + bj);
      }
    }
  }
}

// ---------------- decoder: one wave per label pair ----------------
__global__ __launch_bounds__(256) void decoder_f16(
    const _Float16* __restrict__ zu, const _Float16* __restrict__ zr,
    const int* __restrict__ ls, const int* __restrict__ ld,
    float* __restrict__ outp) {
  const int w = (blockIdx.x * 256 + threadIdx.x) >> 6;
  if (w >= NL) return;
  const int lane = threadIdx.x & 63;
  const int hl = lane & 31;
  const _Float16* src = (lane >= 32) ? (zr + (size_t)ld[w] * OUT_D)
                                     : (zu + (size_t)ls[w] * OUT_D);
  half2v v = ((const half2v*)src)[hl];
  float x0 = (float)v[0], x1 = (float)v[1];
  float y0 = __shfl_xor(x0, 32, 64);
  float y1 = __shfl_xor(x1, 32, 64);
  float nx = x0 * x0 + x1 * x1;
  float ny = y0 * y0 + y1 * y1;
  float ab = x0 * y0 + x1 * y1;
#pragma unroll
  for (int o = 16; o > 0; o >>= 1) {
    nx += __shfl_xor(nx, o, 64);
    ny += __shfl_xor(ny, o, 64);
    ab += __shfl_xor(ab, o, 64);
  }
  if (lane == 0) {
    float denom = fmaxf(sqrtf(nx), 1e-12f) * fmaxf(sqrtf(ny), 1e-12f);
    outp[w] = ab / denom;
  }
}

extern "C" void kernel_launch(void* const* d_in, const int* in_sizes, int n_in,
                              void* d_out, int out_size, void* d_ws, size_t ws_size,
                              hipStream_t stream) {
  (void)in_sizes; (void)n_in; (void)out_size; (void)ws_size;
  const float* x_user   = (const float*)d_in[0];
  const float* x_recipe = (const float*)d_in[1];
  const int* edge_src   = (const int*)d_in[2];
  const int* edge_dst   = (const int*)d_in[3];
  const int* lbl_src    = (const int*)d_in[4];
  const int* lbl_dst    = (const int*)d_in[5];
  const float* Wu       = (const float*)d_in[6];
  const float* bu       = (const float*)d_in[7];
  const float* Wrec     = (const float*)d_in[8];
  const float* brec     = (const float*)d_in[9];
  const float* c1_ur_Wl = (const float*)d_in[10];
  const float* c1_ur_bl = (const float*)d_in[11];
  const float* c1_ur_Wr = (const float*)d_in[12];
  const float* c1_ru_Wl = (const float*)d_in[13];
  const float* c1_ru_bl = (const float*)d_in[14];
  const float* c1_ru_Wr = (const float*)d_in[15];
  const float* c2_ur_Wl = (const float*)d_in[16];
  const float* c2_ur_bl = (const float*)d_in[17];
  const float* c2_ur_Wr = (const float*)d_in[18];
  const float* c2_ru_Wl = (const float*)d_in[19];
  const float* c2_ru_bl = (const float*)d_in[20];
  const float* c2_ru_Wr = (const float*)d_in[21];
  float* out = (float*)d_out;

  char* ws = (char*)d_ws;
  size_t off = 0;
  auto take = [&](size_t bytes) -> void* {
    void* p = ws + off;
    off = (off + bytes + 255) & ~(size_t)255;
    return p;
  };
  _Float16* hu    = (_Float16*)take((size_t)N_USERS * H * 2);    // 25.6 MB
  _Float16* hr    = (_Float16*)take((size_t)N_RECIPES * H * 2);  // 12.8 MB
  _Float16* meanr = (_Float16*)take((size_t)N_RECIPES * H * 2);  // 12.8 MB
  _Float16* r1    = (_Float16*)take((size_t)N_RECIPES * H * 2);
  _Float16* u1    = (_Float16*)take((size_t)N_USERS * H * 2);
  int* off_r  = (int*)take((size_t)(N_RECIPES + 1) * 4);
  int* off_u  = (int*)take((size_t)(N_USERS + 1) * 4);
  int* eidx_r = (int*)take((size_t)NE * 4);
  int* eidx_u = (int*)take((size_t)NE * 4);
  unsigned* stage_r = (unsigned*)take((size_t)NE * 4);
  unsigned* stage_u = (unsigned*)take((size_t)NE * 4);
  int* btot    = (int*)take(512 * 4);
  int* bbase_r = (int*)take(257 * 4);
  int* bbase_u = (int*)take(257 * 4);
  int* bcur_r  = (int*)take(256 * 4);
  int* bcur_u  = (int*)take(256 * 4);
  _Float16* Wu_h     = (_Float16*)take(H * DU * 2);
  _Float16* Wrec_h   = (_Float16*)take(H * DR * 2);
  _Float16* c1urWl_h = (_Float16*)take(H * H * 2);
  _Float16* c1urWr_h = (_Float16*)take(H * H * 2);
  _Float16* c1ruWl_h = (_Float16*)take(H * H * 2);
  _Float16* c1ruWr_h = (_Float16*)take(H * H * 2);
  _Float16* c2urWl_h = (_Float16*)take(OUT_D * H * 2);
  _Float16* c2urWr_h = (_Float16*)take(OUT_D * H * 2);
  _Float16* c2ruWl_h = (_Float16*)take(OUT_D * H * 2);
  _Float16* c2ruWr_h = (_Float16*)take(OUT_D * H * 2);
  // dead-buffer aliases (schedule-verified)
  _Float16* t_r1 = meanr;                           // written after conv1-r GEMM reads meanr
  _Float16* t_u2 = hr;                              // hr last read in conv1u-merge GEMM
  _Float16* t_r2 = meanr;                           // meanr(t_r1) last read in agg1u
  _Float16* zr   = hu;                              // hu last read in conv1u-merge GEMM
  _Float16* zu   = hu + (size_t)N_RECIPES * OUT_D;  // disjoint from zr within hu region

  // ---- 1. weight conversion (+ btot zero)
  WPack wp;
  wp.src[0] = Wu;       wp.dst[0] = Wu_h;      wp.sz4[0] = H * DU / 4;
  wp.src[1] = Wrec;     wp.dst[1] = Wrec_h;    wp.sz4[1] = H * DR / 4;
  wp.src[2] = c1_ur_Wl; wp.dst[2] = c1urWl_h;  wp.sz4[2] = H * H / 4;
  wp.src[3] = c1_ur_Wr; wp.dst[3] = c1urWr_h;  wp.sz4[3] = H * H / 4;
  wp.src[4] = c1_ru_Wl; wp.dst[4] = c1ruWl_h;  wp.sz4[4] = H * H / 4;
  wp.src[5] = c1_ru_Wr; wp.dst[5] = c1ruWr_h;  wp.sz4[5] = H * H / 4;
  wp.src[6] = c2_ur_Wl; wp.dst[6] = c2urWl_h;  wp.sz4[6] = OUT_D * H / 4;
  wp.src[7] = c2_ur_Wr; wp.dst[7] = c2urWr_h;  wp.sz4[7] = OUT_D * H / 4;
  wp.src[8] = c2_ru_Wl; wp.dst[8] = c2ruWl_h;  wp.sz4[8] = OUT_D * H / 4;
  wp.src[9] = c2_ru_Wr; wp.dst[9] = c2ruWr_h;  wp.sz4[9] = OUT_D * H / 4;
  wp.btot = btot;
  convert_weights<<<dim3(32, 10), 256, 0, stream>>>(wp);

  // ---- 2-5. CSR build
  csr_phase0<<<512, 256, 0, stream>>>(edge_src, edge_dst, btot);
  csr_bscan<<<1, 256, 0, stream>>>(btot, bbase_r, bcur_r, off_r, bbase_u, bcur_u, off_u);
  csr_phase1<<<(NE + 2047) / 2048, 256, 0, stream>>>(edge_src, edge_dst, bcur_r, bcur_u,
                                                     stage_r, stage_u);
  csr_phase2<<<2 * NBKT, 256, 0, stream>>>(stage_r, bbase_r, off_r, eidx_r,
                                           stage_u, bbase_u, off_u, eidx_u);

  // ---- 6. input projections (merged)
  {
    GParts P;
    P.A[0] = x_user;   P.W[0] = Wu_h;   P.bias[0] = bu;   P.out[0] = hu;
    P.M[0] = N_USERS;  P.K[0] = DU;     P.blk0[0] = 0;
    P.A[1] = x_recipe; P.W[1] = Wrec_h; P.bias[1] = brec; P.out[1] = hr;
    P.M[1] = N_RECIPES; P.K[1] = DR;    P.blk0[1] = 782;
    P.A[2] = P.A[3] = nullptr; P.W[2] = P.W[3] = nullptr;
    P.bias[2] = P.bias[3] = nullptr; P.out[2] = P.out[3] = nullptr;
    P.M[2] = P.M[3] = 1; P.K[2] = P.K[3] = 32;
    P.blk0[2] = P.blk0[3] = 0x7fffffff;
    gemm_parts<128, true><<<782 + 391, 256, 0, stream>>>(P);
  }

  // ---- 7. conv1 recipe-side aggregation (mean-first)
  agg_mean2<H, false, false><<<(N_RECIPES * 16 + 255) / 256, 256, 0, stream>>>(
      hu, off_r, eidx_r, meanr, N_RECIPES);
  // ---- 8. conv1 recipe GEMM: r1 = relu(meanr@Wl + hr@Wr + b)
  gemm_direct<128, H, true, true, true, false><<<(N_RECIPES + 127) / 128, 256, 0, stream>>>(
      meanr, c1urWl_h, hr, c1urWr_h, c1_ur_bl, r1, N_RECIPES);
  // ---- 9. conv1 user-side transforms (merged): t_r1 = hr@Wl ; u1 = hu@Wr + b
  {
    GParts P;
    P.A[0] = hr; P.W[0] = c1ruWl_h; P.bias[0] = nullptr;  P.out[0] = t_r1;
    P.M[0] = N_RECIPES; P.K[0] = H; P.blk0[0] = 0;
    P.A[1] = hu; P.W[1] = c1ruWr_h; P.bias[1] = c1_ru_bl; P.out[1] = u1;
    P.M[1] = N_USERS;   P.K[1] = H; P.blk0[1] = 391;
    P.A[2] = P.A[3] = nullptr; P.W[2] = P.W[3] = nullptr;
    P.bias[2] = P.bias[3] = nullptr; P.out[2] = P.out[3] = nullptr;
    P.M[2] = P.M[3] = 1; P.K[2] = P.K[3] = 32;
    P.blk0[2] = P.blk0[3] = 0x7fffffff;
    gemm_parts<128, false><<<391 + 782, 256, 0, stream>>>(P);
  }
  // ---- 10. conv1 user-side aggregation: u1 = relu(u1 + mean(t_r1))
  agg_mean2<H, true, true><<<(N_USERS * 16 + 255) / 256, 256, 0, stream>>>(
      t_r1, off_u, eidx_u, u1, N_USERS);

  // ---- 11. conv2 transforms (4 GEMMs merged, BN=64/BM=256)
  {
    GParts P;
    P.A[0] = u1; P.W[0] = c2urWl_h; P.bias[0] = nullptr;  P.out[0] = t_u2;
    P.M[0] = N_USERS;   P.K[0] = H; P.blk0[0] = 0;
    P.A[1] = r1; P.W[1] = c2urWr_h; P.bias[1] = c2_ur_bl; P.out[1] = zr;
    P.M[1] = N_RECIPES; P.K[1] = H; P.blk0[1] = 391;
    P.A[2] = r1; P.W[2] = c2ruWl_h; P.bias[2] = nullptr;  P.out[2] = t_r2;
    P.M[2] = N_RECIPES; P.K[2] = H; P.blk0[2] = 587;
    P.A[3] = u1; P.W[3] = c2ruWr_h; P.bias[3] = c2_ru_bl; P.out[3] = zu;
    P.M[3] = N_USERS;   P.K[3] = H; P.blk0[3] = 783;
    gemm_parts<64, false><<<391 + 196 + 196 + 391, 256, 0, stream>>>(P);
  }
  // ---- 12. conv2 aggregations (merged): zr += mean(t_u2) ; zu += mean(t_r2)
  agg_mean_dual64<<<((N_RECIPES + N_USERS) * 8 + 255) / 256, 256, 0, stream>>>(
      t_u2, off_r, eidx_r, zr, t_r2, off_u, eidx_u, zu);

  // ---- 13. decoder
  decoder_f16<<<((size_t)NL * 64 + 255) / 256, 256, 0, stream>>>(zu, zr, lbl_src, lbl_dst, out);
}